// Round 3
// baseline (427.317 us; speedup 1.0000x reference)
//
#include <hip/hip_runtime.h>
#include <math.h>

// NerfHead: fused ray-march + trilinear + online transmittance + 3 losses.
// R2b: persistent-wave ray stealing (grid 1280 = 20 waves/CU flat, balances the
//     drain tail that held avg occupancy at 34.7%), ballot-assisted phase-C
//     (serial only over non-"big" steps: inner steps always exceed DIST_THRES
//     => forced reset, bit-exact decomposition), chunk hot-mask to skip
//     out-of-z-slab chunks (alpha == const A0 there, dens==0 exactly),
//     paired density loads (dwordx2), int32 addressing with immediate offsets.
// Wave-private LDS phases; inter-wave __syncthreads removed (lgkmcnt fences).
// launch_bounds (256,5): 102-VGPR cap avoids spills (R2 had (256,6)=85 cap).
// Global accumulators in d_ws: [0]=sum_wy_nll [1]=sum_wy [2]=sum_ent
// [3]=n_valid [4]=sum_bi [5]=sum_w2 [6]=n_pk  [8]=ray counter (int)

#define DXX 200
#define DYY 200
#define DZZ 16
#define NC 17
#define S_TOT 416
#define N_IN 390
#define CHUNKS 7
#define RPB 4       // waves (rays in flight) per block
#define NBLOCKS 1280

typedef float v4u __attribute__((ext_vector_type(4), aligned(4), may_alias));
typedef float v2u __attribute__((ext_vector_type(2), aligned(4), may_alias));

__constant__ double c_freq[NC] = {1163161.0, 2309034.0, 188743.0, 2997643.0,
  20317180.0, 852476.0, 243808.0, 2457947.0, 497017.0, 2731022.0, 7224789.0,
  214411435.0, 5565043.0, 63191967.0, 76098082.0, 128860031.0, 141625221.0};

__device__ __forceinline__ float iscan_add(float x, int lane) {
#pragma unroll
  for (int off = 1; off < 64; off <<= 1) {
    float y = __shfl_up(x, off);
    if (lane >= off) x += y;
  }
  return x;
}
__device__ __forceinline__ float iscan_mul(float x, int lane) {
#pragma unroll
  for (int off = 1; off < 64; off <<= 1) {
    float y = __shfl_up(x, off);
    if (lane >= off) x *= y;
  }
  return x;
}

__global__ __launch_bounds__(256) void nerf_zero(float* acc) {
  if (threadIdx.x < 16) acc[threadIdx.x] = 0.f;
}

__global__ __launch_bounds__(256, 5) void nerf_main(
    const float* __restrict__ density,
    const float* __restrict__ semantic,
    const float* __restrict__ rays,
    const float* __restrict__ bda,
    float* __restrict__ acc_g,
    int nrays) {
  __shared__ float s_t[CHUNKS * 64];
  __shared__ float s_dist[RPB][S_TOT];
  __shared__ unsigned long long s_keep[RPB][CHUNKS];
  __shared__ unsigned long long s_big[RPB][CHUNKS];
  __shared__ float s_acc[8];

  const int lane = threadIdx.x & 63;
  const int wv = threadIdx.x >> 6;

  // ---- constants matching the reference's numpy derivations ----
  const double BG = (double)(1.0f / 39.0f);
  const float BGf = (float)BG;
  const float DTH = (float)((2.0 + 2.0 * BG) / 200.0 * 0.5 * 0.95);
  const float xminf = (float)(-1.0 - BG);
  const float zf = 6.4f / 80.0f;
  const float sxy = 199.0f / ((float)(1.0 + BG) - xminf);
  const float szc = 15.0f / (zf + zf);
  const float ACTS = -13.815509557964274f;

  if (threadIdx.x < 8) s_acc[threadIdx.x] = 0.f;

  for (int i = threadIdx.x; i < CHUNKS * 64; i += 256) {
    double td;
    if (i < N_IN) {
      td = (2.0 * i + 1.0) / 390.0;
    } else {
      int j = i - N_IN;
      const double stp = (1.0 / 64.0 - 1.0) / 26.0;
      double l0 = 1.0 + j * stp;
      double l1 = (j + 1 >= 26) ? (1.0 / 64.0) : (1.0 + (j + 1) * stp);
      td = 1.0 / l0 + 1.0 / l1;
    }
    s_t[i] = (float)td;
  }
  __syncthreads();

  // out-of-slab alpha: dens==0 exactly -> same expf chain as in-loop
  const float A0 = -expm1f(-0.5f * log1pf(expf(ACTS)));

  const float b00 = bda[0], b01 = bda[1], b02 = bda[2];
  const float b10 = bda[3], b11 = bda[4], b12 = bda[5];
  const float b20 = bda[6], b21 = bda[7], b22 = bda[8];

  int* cnt = (int*)(acc_g + 8);

  for (;;) {
    int ray;
    if (lane == 0) ray = atomicAdd(cnt, 1);
    ray = __shfl(ray, 0);
    if (ray >= nrays) break;

    const float* rp = rays + (size_t)ray * 10;
    float dep = rp[2];
    bool doit = (dep > 0.f) && (dep <= 52.f);
    if (!doit) continue;
    int ysem = (int)rp[3];
    ysem = ysem < 0 ? 0 : (ysem > NC - 1 ? NC - 1 : ysem);
    const float czc = (-1.0f + 5.4f) * 0.5f;
    float rox = rp[4] / 39.0f;
    float roy = rp[5] / 39.0f;
    float roz = (rp[6] - czc) / 39.0f;
    float d0 = rp[7], d1 = rp[8], d2 = rp[9];
    float rn = sqrtf(d0 * d0 + d1 * d1 + d2 * d2);
    float rdx = d0 / rn, rdy = d1 / rn, rdz = d2 / rn;

    auto compute_pt = [&](int s, float& tx, float& ty, float& tz, float& tt,
                          bool& inner) {
      tt = s_t[s];
      float qx = rox + rdx * tt;
      float qy = roy + rdy * tt;
      float qz = roz + rdz * tt;
      float nr = sqrtf(qx * qx + qy * qy + qz * qz);
      inner = (nr <= 1.0f) && (s < S_TOT);
      if (nr > 1.0f) {
        float sc = (1.0f + BGf - BGf / nr) / nr;
        qx *= sc; qy *= sc; qz *= sc;
      }
      tx = b00 * qx + b01 * qy + b02 * qz;
      ty = b10 * qx + b11 * qy + b12 * qz;
      tz = b20 * qx + b21 * qy + b22 * qz;
    };

    // ---- phase A/B: pts, dist, ballots, density->alpha per chunk ----
    float a_r[CHUNKS];
    int hotmask = 0;
#pragma unroll
    for (int c = 0; c < CHUNKS; c++) {
      int s = c * 64 + lane;
      float tx, ty, tz, tt; bool inner;
      compute_pt(s, tx, ty, tz, tt, inner);
      unsigned long long bal = __ballot(inner);
      float nx = __shfl(tx, lane + 1);
      float ny = __shfl(ty, lane + 1);
      float nz = __shfl(tz, lane + 1);
      if (c < CHUNKS - 1) {
        float hx, hy, hz, ht; bool hi;
        compute_pt((c + 1) * 64, hx, hy, hz, ht, hi);
        if (lane == 63) { nx = hx; ny = hy; nz = hz; }
      }
      float ex = nx - tx, ey = ny - ty, ez = nz - tz;
      float dd = sqrtf(ex * ex + ey * ey + ez * ez);
      bool dlive = (s < S_TOT - 1);
      if (dlive) s_dist[wv][s] = dd;
      unsigned long long db = __ballot(dlive && (dd > DTH));
      if (lane == 0) { s_keep[wv][c] = bal; s_big[wv][c] = db; }

      bool live = s < S_TOT;
      float gz = (tz + zf) * szc;
      float hzf = floorf(gz);
      int iz = (int)hzf;
      float fz = gz - hzf;
      bool vz0 = (unsigned)iz < (unsigned)DZZ;
      bool vz1 = (unsigned)(iz + 1) < (unsigned)DZZ;
      bool zv = live && (vz0 || vz1);
      float a;
      if (__any(zv)) {
        hotmask |= (1 << c);
        float gx = (tx - xminf) * sxy;
        float gy = (ty - xminf) * sxy;
        float hxf = floorf(gx), hyf = floorf(gy);
        int ix = (int)hxf, iy = (int)hyf;
        float fx = gx - hxf, fy = gy - hyf;
        float wx0 = 1.f - fx, wy0 = 1.f - fy, wz0 = 1.f - fz;
        bool vx0 = (unsigned)ix < (unsigned)DXX, vx1 = (unsigned)(ix + 1) < (unsigned)DXX;
        bool vy0 = (unsigned)iy < (unsigned)DYY, vy1 = (unsigned)(iy + 1) < (unsigned)DYY;
        float dens = 0.f;
        if (zv) {
          int base = (ix * DYY + iy) * DZZ + iz;
          const float* p0 = density + base;
          if (vx0 && vx1 && vy0 && vy1 && vz0 && vz1) {
            v2u d00 = *(const v2u*)(p0);
            v2u d01 = *(const v2u*)(p0 + DZZ);
            v2u d10 = *(const v2u*)(p0 + DYY * DZZ);
            v2u d11 = *(const v2u*)(p0 + DYY * DZZ + DZZ);
            dens += wx0 * wy0 * wz0 * d00[0];
            dens += wx0 * wy0 * fz  * d00[1];
            dens += wx0 * fy  * wz0 * d01[0];
            dens += wx0 * fy  * fz  * d01[1];
            dens += fx  * wy0 * wz0 * d10[0];
            dens += fx  * wy0 * fz  * d10[1];
            dens += fx  * fy  * wz0 * d11[0];
            dens += fx  * fy  * fz  * d11[1];
          } else {
            if (vx0 && vy0 && vz0) dens += wx0 * wy0 * wz0 * p0[0];
            if (vx0 && vy0 && vz1) dens += wx0 * wy0 * fz  * p0[1];
            if (vx0 && vy1 && vz0) dens += wx0 * fy  * wz0 * p0[DZZ];
            if (vx0 && vy1 && vz1) dens += wx0 * fy  * fz  * p0[DZZ + 1];
            if (vx1 && vy0 && vz0) dens += fx  * wy0 * wz0 * p0[DYY * DZZ];
            if (vx1 && vy0 && vz1) dens += fx  * wy0 * fz  * p0[DYY * DZZ + 1];
            if (vx1 && vy1 && vz0) dens += fx  * fy  * wz0 * p0[DYY * DZZ + DZZ];
            if (vx1 && vy1 && vz1) dens += fx  * fy  * fz  * p0[DYY * DZZ + DZZ + 1];
          }
        }
        float u = expf(dens + ACTS);
        a = -expm1f(-0.5f * log1pf(u));
      } else {
        a = A0;
      }
      a_r[c] = a;
    }

    // ---- phase C: resetting distance scan, serial ONLY over non-big steps.
    // big step (dist > DTH) forces over=1, cum=0 regardless of incoming cum
    // (cum>=0 and f32 add of non-negatives >= max operand) -> bit-exact.
    asm volatile("s_waitcnt lgkmcnt(0)" ::: "memory");
    if (lane == 0) {
      float cum = 0.f;
      int prev = 0;
      unsigned long long carrybit = 0;
#pragma unroll
      for (int c = 0; c < CHUNKS; c++) {
        unsigned long long inner = s_keep[wv][c];
        unsigned long long db = s_big[wv][c];
        unsigned long long big = (db << 1) | carrybit;
        carrybit = db >> 63;
        unsigned long long valid = ~0ull;
        if (c == 0) valid &= ~1ull;                       // s=0 is not a step
        if (c == CHUNKS - 1) valid &= 0x00000000FFFFFFFFull;  // s<=415
        big &= valid;
        unsigned long long k = inner | big;
        unsigned long long nb = valid & ~big;
        while (nb) {
          int b = __ffsll((unsigned long long)nb) - 1;
          nb &= nb - 1;
          int s = c * 64 + b;
          if (s - 1 != prev) cum = 0.f;   // gap => previous step was big (reset)
          cum += s_dist[wv][s - 1];
          if (cum > DTH) { cum = 0.f; k |= 1ull << b; }
          prev = s;
        }
        s_keep[wv][c] = k;
      }
    }
    asm volatile("s_waitcnt lgkmcnt(0)" ::: "memory");

    // ---- phase D: transmittance + distortion scans (pure VALU/DS) ----
    float out_sem[NC];
#pragma unroll
    for (int j = 0; j < NC; j++) out_sem[j] = 0.f;
    float w_r[CHUNKS];
    float carry = 1.f, carryW = 0.f, carryWM = 0.f;
    float sum_bi = 0.f, sum_w2 = 0.f, pkcf = 0.f;
#pragma unroll
    for (int c = 0; c < CHUNKS; c++) {
      int s = c * 64 + lane;
      float tt = s_t[s];
      float m_ = 1.0f - 1.0f / (1.0f + tt);
      bool keep = (s_keep[wv][c] >> lane) & 1ull;
      float ar = a_r[c];
      float a = (keep && (ar > 1e-7f)) ? ar : 0.f;

      float om = 1.f - a;
      float ip = iscan_mul(om, lane);
      float ex = __shfl_up(ip, 1); if (lane == 0) ex = 1.f;
      float wgt = a * carry * ex;
      carry *= __shfl(ip, 63);
      float w = (wgt > 1e-7f) ? wgt : 0.f;
      if (w > 0.f) pkcf += 1.f;

      float wm = w * m_;
      float isw = iscan_add(w, lane);
      float iswm = iscan_add(wm, lane);
      float exw = __shfl_up(isw, 1);  if (lane == 0) exw = 0.f;
      float exwm = __shfl_up(iswm, 1); if (lane == 0) exwm = 0.f;
      sum_bi += 2.f * w * (m_ * (carryW + exw) - (carryWM + exwm));
      sum_w2 += w * w;
      carryW += __shfl(isw, 63);
      carryWM += __shfl(iswm, 63);
      w_r[c] = w;
    }

    // ---- phase E: semantic gather, hot chunks only ----
#pragma unroll
    for (int c = 0; c < CHUNKS; c++) {
      if (!((hotmask >> c) & 1)) continue;
      if (!__any(w_r[c] > 0.f)) continue;
      int s = c * 64 + lane;
      float tx, ty, tz, tt; bool inner;
      compute_pt(s, tx, ty, tz, tt, inner);
      float w = w_r[c];
      if (w > 0.f) {
        float gx = (tx - xminf) * sxy;
        float gy = (ty - xminf) * sxy;
        float gz = (tz + zf) * szc;
        float hxf = floorf(gx), hyf = floorf(gy), hzf = floorf(gz);
        int ix = (int)hxf, iy = (int)hyf, iz = (int)hzf;
        float fx = gx - hxf, fy = gy - hyf, fz = gz - hzf;
        float wx0 = 1.f - fx, wy0 = 1.f - fy, wz0 = 1.f - fz;
        bool vx0 = (unsigned)ix < (unsigned)DXX, vx1 = (unsigned)(ix + 1) < (unsigned)DXX;
        bool vy0 = (unsigned)iy < (unsigned)DYY, vy1 = (unsigned)(iy + 1) < (unsigned)DYY;
        bool vz0 = (unsigned)iz < (unsigned)DZZ, vz1 = (unsigned)(iz + 1) < (unsigned)DZZ;
        int base17 = ((ix * DYY + iy) * DZZ + iz) * NC;
        const float* sp0 = semantic + base17;           // corner (0,0,0)
        const float* sp1 = sp0 + DYY * DZZ * NC;        // corner (1,0,0)
#define SEM_ACC(PTR, WC)                                                        \
        { float wc = (WC);                                                      \
          const v4u* q = (const v4u*)(PTR);                                     \
          v4u q0 = q[0], q1 = q[1], q2 = q[2], q3 = q[3];                       \
          float qs = (PTR)[16];                                                 \
          out_sem[0]  += wc * q0[0];  out_sem[1]  += wc * q0[1];                \
          out_sem[2]  += wc * q0[2];  out_sem[3]  += wc * q0[3];                \
          out_sem[4]  += wc * q1[0];  out_sem[5]  += wc * q1[1];                \
          out_sem[6]  += wc * q1[2];  out_sem[7]  += wc * q1[3];                \
          out_sem[8]  += wc * q2[0];  out_sem[9]  += wc * q2[1];                \
          out_sem[10] += wc * q2[2];  out_sem[11] += wc * q2[3];                \
          out_sem[12] += wc * q3[0];  out_sem[13] += wc * q3[1];                \
          out_sem[14] += wc * q3[2];  out_sem[15] += wc * q3[3];                \
          out_sem[16] += wc * qs; }
        if (vx0 && vx1 && vy0 && vy1 && vz0 && vz1) {
          SEM_ACC(sp0,                 w * wx0 * wy0 * wz0)
          SEM_ACC(sp0 + NC,            w * wx0 * wy0 * fz)
          SEM_ACC(sp0 + DZZ * NC,      w * wx0 * fy  * wz0)
          SEM_ACC(sp0 + DZZ * NC + NC, w * wx0 * fy  * fz)
          SEM_ACC(sp1,                 w * fx  * wy0 * wz0)
          SEM_ACC(sp1 + NC,            w * fx  * wy0 * fz)
          SEM_ACC(sp1 + DZZ * NC,      w * fx  * fy  * wz0)
          SEM_ACC(sp1 + DZZ * NC + NC, w * fx  * fy  * fz)
        } else {
          if (vx0 && vy0 && vz0) SEM_ACC(sp0,                 w * wx0 * wy0 * wz0)
          if (vx0 && vy0 && vz1) SEM_ACC(sp0 + NC,            w * wx0 * wy0 * fz)
          if (vx0 && vy1 && vz0) SEM_ACC(sp0 + DZZ * NC,      w * wx0 * fy  * wz0)
          if (vx0 && vy1 && vz1) SEM_ACC(sp0 + DZZ * NC + NC, w * wx0 * fy  * fz)
          if (vx1 && vy0 && vz0) SEM_ACC(sp1,                 w * fx  * wy0 * wz0)
          if (vx1 && vy0 && vz1) SEM_ACC(sp1 + NC,            w * fx  * wy0 * fz)
          if (vx1 && vy1 && vz0) SEM_ACC(sp1 + DZZ * NC,      w * fx  * fy  * wz0)
          if (vx1 && vy1 && vz1) SEM_ACC(sp1 + DZZ * NC + NC, w * fx  * fy  * fz)
        }
#undef SEM_ACC
      }
    }

    // ---- phase G: wave reductions + per-ray epilogue -> block LDS acc ----
    float r0 = sum_bi, r1 = sum_w2, r2 = pkcf;
#pragma unroll
    for (int off = 32; off >= 1; off >>= 1) {
      r0 += __shfl_xor(r0, off);
      r1 += __shfl_xor(r1, off);
      r2 += __shfl_xor(r2, off);
#pragma unroll
      for (int j = 0; j < NC; j++) out_sem[j] += __shfl_xor(out_sem[j], off);
    }
    if (lane == 0) {
      float M = out_sem[0];
#pragma unroll
      for (int j = 1; j < NC; j++) M = fmaxf(M, out_sem[j]);
      float se = 0.f;
#pragma unroll
      for (int j = 0; j < NC; j++) se += expf(out_sem[j] - M);
      float lse = M + logf(se);
      float sy = 0.f;
#pragma unroll
      for (int j = 0; j < NC; j++) if (j == ysem) sy = out_sem[j];
      float nll = lse - sy;
      float cw = (float)(1.0 / log(c_freq[ysem] + 0.001));
      float p = fminf(fmaxf(carry, 1e-6f), 1.0f - 1e-6f);
      float ent = -(p * logf(p) + (1.f - p) * logf(1.f - p));
      atomicAdd(&s_acc[0], cw * nll);
      atomicAdd(&s_acc[1], cw);
      atomicAdd(&s_acc[2], ent);
      atomicAdd(&s_acc[3], 1.f);
      atomicAdd(&s_acc[4], r0);
      atomicAdd(&s_acc[5], r1);
      atomicAdd(&s_acc[6], r2);
    }
  }

  __syncthreads();
  if (threadIdx.x == 0 && s_acc[3] > 0.f) {
#pragma unroll
    for (int i = 0; i < 7; i++) atomicAdd(&acc_g[i], s_acc[i]);
  }
}

__global__ __launch_bounds__(64) void nerf_fin(const float* __restrict__ acc,
                                               float* __restrict__ out) {
  if (threadIdx.x == 0) {
    float ls = acc[0] / fmaxf(acc[1], 1e-12f);
    float nv = fmaxf(acc[3], 1.f);
    float le = acc[2] / nv;
    float nmax = fmaxf(acc[6], 1.f);
    float ld = (acc[4] + (1.f / 3.f) * (1.f / nmax) * acc[5]) / nv;
    out[0] = 1.0f * ls;    // W_SEM
    out[1] = 0.01f * le;   // W_ENT
    out[2] = 0.01f * ld;   // W_DIST
  }
}

extern "C" void kernel_launch(void* const* d_in, const int* in_sizes, int n_in,
                              void* d_out, int out_size, void* d_ws, size_t ws_size,
                              hipStream_t stream) {
  const float* density = (const float*)d_in[0];
  const float* semantic = (const float*)d_in[1];
  const float* rays = (const float*)d_in[2];
  const float* bda = (const float*)d_in[3];
  float* out = (float*)d_out;
  float* acc = (float*)d_ws;
  int nrays = in_sizes[2] / 10;
  nerf_zero<<<1, 256, 0, stream>>>(acc);
  int nb = (nrays + RPB - 1) / RPB;
  if (nb > NBLOCKS) nb = NBLOCKS;
  nerf_main<<<nb, 64 * RPB, 0, stream>>>(density, semantic, rays, bda, acc, nrays);
  nerf_fin<<<1, 64, 0, stream>>>(acc, out);
}

// Round 6
// 382.382 us; speedup vs baseline: 1.1175x; 1.1175x over previous
//
#include <hip/hip_runtime.h>
#include <math.h>

// NerfHead: fused ray-march + trilinear + online transmittance + 3 losses.
// R3: R1's merged phase-D/E/F single loop (spill-free structure, 48 VGPR)
//     + persistent-wave ray stealing (balances the drain tail; R1 avg occ 34.7%)
//     + ballot-assisted phase-C (serial only over non-"big" steps; bit-exact)
//     + wave-uniform keepmask chunk skip in the merged loop (exact identity).
// R2b lesson: splitting scans from semantic gather made out_sem[17] spill to
// scratch (152MB writes/dispatch => 100% spill-bound). Merged loop avoids it.
// No launch_bounds occupancy floor: let the allocator use what it needs.
// Global accumulators in d_ws: [0]=sum_wy_nll [1]=sum_wy [2]=sum_ent
// [3]=n_valid [4]=sum_bi [5]=sum_w2 [6]=n_pk  [8]=ray counter (int)

#define DXX 200
#define DYY 200
#define DZZ 16
#define NC 17
#define S_TOT 416
#define N_IN 390
#define CHUNKS 7
#define RPB 4       // waves (rays in flight) per block
#define NBLOCKS 2048

typedef float v4u __attribute__((ext_vector_type(4), aligned(4), may_alias));
typedef float v2u __attribute__((ext_vector_type(2), aligned(4), may_alias));

__constant__ double c_freq[NC] = {1163161.0, 2309034.0, 188743.0, 2997643.0,
  20317180.0, 852476.0, 243808.0, 2457947.0, 497017.0, 2731022.0, 7224789.0,
  214411435.0, 5565043.0, 63191967.0, 76098082.0, 128860031.0, 141625221.0};

__device__ __forceinline__ float iscan_add(float x, int lane) {
#pragma unroll
  for (int off = 1; off < 64; off <<= 1) {
    float y = __shfl_up(x, off);
    if (lane >= off) x += y;
  }
  return x;
}
__device__ __forceinline__ float iscan_mul(float x, int lane) {
#pragma unroll
  for (int off = 1; off < 64; off <<= 1) {
    float y = __shfl_up(x, off);
    if (lane >= off) x *= y;
  }
  return x;
}

__global__ __launch_bounds__(256) void nerf_zero(float* acc) {
  if (threadIdx.x < 16) acc[threadIdx.x] = 0.f;
}

__global__ __launch_bounds__(256) void nerf_main(
    const float* __restrict__ density,
    const float* __restrict__ semantic,
    const float* __restrict__ rays,
    const float* __restrict__ bda,
    float* __restrict__ acc_g,
    int nrays) {
  __shared__ float s_t[CHUNKS * 64];
  __shared__ float s_dist[RPB][S_TOT];
  __shared__ unsigned long long s_keep[RPB][CHUNKS];
  __shared__ unsigned long long s_big[RPB][CHUNKS];
  __shared__ float s_acc[8];

  const int lane = threadIdx.x & 63;
  const int wv = threadIdx.x >> 6;

  // ---- constants matching the reference's numpy derivations ----
  const double BG = (double)(1.0f / 39.0f);
  const float BGf = (float)BG;
  const float DTH = (float)((2.0 + 2.0 * BG) / 200.0 * 0.5 * 0.95);
  const float xminf = (float)(-1.0 - BG);
  const float zf = 6.4f / 80.0f;
  const float sxy = 199.0f / ((float)(1.0 + BG) - xminf);
  const float szc = 15.0f / (zf + zf);
  const float ACTS = -13.815509557964274f;

  if (threadIdx.x < 8) s_acc[threadIdx.x] = 0.f;

  for (int i = threadIdx.x; i < CHUNKS * 64; i += 256) {
    double td;
    if (i < N_IN) {
      td = (2.0 * i + 1.0) / 390.0;
    } else {
      int j = i - N_IN;
      const double stp = (1.0 / 64.0 - 1.0) / 26.0;
      double l0 = 1.0 + j * stp;
      double l1 = (j + 1 >= 26) ? (1.0 / 64.0) : (1.0 + (j + 1) * stp);
      td = 1.0 / l0 + 1.0 / l1;
    }
    s_t[i] = (float)td;
  }
  __syncthreads();

  const float b00 = bda[0], b01 = bda[1], b02 = bda[2];
  const float b10 = bda[3], b11 = bda[4], b12 = bda[5];
  const float b20 = bda[6], b21 = bda[7], b22 = bda[8];

  int* cnt = (int*)(acc_g + 8);

  for (;;) {
    int ray;
    if (lane == 0) ray = atomicAdd(cnt, 1);
    ray = __shfl(ray, 0);
    if (ray >= nrays) break;

    const float* rp = rays + (size_t)ray * 10;
    float dep = rp[2];
    bool doit = (dep > 0.f) && (dep <= 52.f);
    if (!doit) continue;
    int ysem = (int)rp[3];
    ysem = ysem < 0 ? 0 : (ysem > NC - 1 ? NC - 1 : ysem);
    const float czc = (-1.0f + 5.4f) * 0.5f;
    float rox = rp[4] / 39.0f;
    float roy = rp[5] / 39.0f;
    float roz = (rp[6] - czc) / 39.0f;
    float d0 = rp[7], d1 = rp[8], d2 = rp[9];
    float rn = sqrtf(d0 * d0 + d1 * d1 + d2 * d2);
    float rdx = d0 / rn, rdy = d1 / rn, rdz = d2 / rn;

    auto compute_pt = [&](int s, float& tx, float& ty, float& tz, float& tt,
                          bool& inner) {
      tt = s_t[s];
      float qx = rox + rdx * tt;
      float qy = roy + rdy * tt;
      float qz = roz + rdz * tt;
      float nr = sqrtf(qx * qx + qy * qy + qz * qz);
      inner = (nr <= 1.0f) && (s < S_TOT);
      if (nr > 1.0f) {
        float sc = (1.0f + BGf - BGf / nr) / nr;
        qx *= sc; qy *= sc; qz *= sc;
      }
      tx = b00 * qx + b01 * qy + b02 * qz;
      ty = b10 * qx + b11 * qy + b12 * qz;
      tz = b20 * qx + b21 * qy + b22 * qz;
    };

    // ---- phase A/B: pts, inner+big ballots, consecutive distances -> LDS ----
    for (int c = 0; c < CHUNKS; c++) {
      int s = c * 64 + lane;
      float tx, ty, tz, tt; bool inner;
      compute_pt(s, tx, ty, tz, tt, inner);
      unsigned long long bal = __ballot(inner);
      float nx = __shfl(tx, lane + 1);
      float ny = __shfl(ty, lane + 1);
      float nz = __shfl(tz, lane + 1);
      if (c < CHUNKS - 1) {
        float hx, hy, hz, ht; bool hi;
        compute_pt((c + 1) * 64, hx, hy, hz, ht, hi);
        if (lane == 63) { nx = hx; ny = hy; nz = hz; }
      }
      float ex = nx - tx, ey = ny - ty, ez = nz - tz;
      float dd = sqrtf(ex * ex + ey * ey + ez * ez);
      bool dlive = (s < S_TOT - 1);
      if (dlive) s_dist[wv][s] = dd;
      unsigned long long db = __ballot(dlive && (dd > DTH));
      if (lane == 0) { s_keep[wv][c] = bal; s_big[wv][c] = db; }
    }

    // ---- phase C: resetting distance scan, serial ONLY over non-big steps.
    // big step (dist > DTH) forces over=1, cum=0 regardless of incoming cum
    // (f32 add of non-negatives is monotone) -> bit-exact decomposition.
    asm volatile("s_waitcnt lgkmcnt(0)" ::: "memory");
    if (lane == 0) {
      float cum = 0.f;
      int prev = 0;
      unsigned long long carrybit = 0;
#pragma unroll
      for (int c = 0; c < CHUNKS; c++) {
        unsigned long long inner = s_keep[wv][c];
        unsigned long long db = s_big[wv][c];
        unsigned long long big = (db << 1) | carrybit;
        carrybit = db >> 63;
        unsigned long long valid = ~0ull;
        if (c == 0) valid &= ~1ull;                       // s=0 is not a step
        if (c == CHUNKS - 1) valid &= 0x00000000FFFFFFFFull;  // s<=415
        big &= valid;
        unsigned long long k = inner | big;
        unsigned long long nb = valid & ~big;
        while (nb) {
          int b = __ffsll((unsigned long long)nb) - 1;
          nb &= nb - 1;
          int s = c * 64 + b;
          if (s - 1 != prev) cum = 0.f;   // gap => previous step was big (reset)
          cum += s_dist[wv][s - 1];
          if (cum > DTH) { cum = 0.f; k |= 1ull << b; }
          prev = s;
        }
        s_keep[wv][c] = k;
      }
    }
    asm volatile("s_waitcnt lgkmcnt(0)" ::: "memory");

    // ---- phase D/E/F merged: density->alpha, scans, semantic (one loop) ----
    float out_sem[NC];
#pragma unroll
    for (int j = 0; j < NC; j++) out_sem[j] = 0.f;
    float carry = 1.f, carryW = 0.f, carryWM = 0.f;
    float sum_bi = 0.f, sum_w2 = 0.f, pkcf = 0.f;

    for (int c = 0; c < CHUNKS; c++) {
      unsigned long long km = s_keep[wv][c];
      if (km == 0ull) continue;   // exact identity: a==0 => carries unchanged
      int s = c * 64 + lane;
      float tx, ty, tz, tt; bool inner;
      compute_pt(s, tx, ty, tz, tt, inner);
      float m_ = 1.0f - 1.0f / (1.0f + tt);
      bool keep = (km >> lane) & 1ull;

      float gx = (tx - xminf) * sxy;
      float gy = (ty - xminf) * sxy;
      float gz = (tz + zf) * szc;
      float hxf = floorf(gx), hyf = floorf(gy), hzf = floorf(gz);
      int ix = (int)hxf, iy = (int)hyf, iz = (int)hzf;
      float fx = gx - hxf, fy = gy - hyf, fz = gz - hzf;
      float wx0 = 1.f - fx, wy0 = 1.f - fy, wz0 = 1.f - fz;
      bool vx0 = (unsigned)ix < (unsigned)DXX, vx1 = (unsigned)(ix + 1) < (unsigned)DXX;
      bool vy0 = (unsigned)iy < (unsigned)DYY, vy1 = (unsigned)(iy + 1) < (unsigned)DYY;
      bool vz0 = (unsigned)iz < (unsigned)DZZ, vz1 = (unsigned)(iz + 1) < (unsigned)DZZ;

      float a = 0.f;
      if (keep) {
        float dens = 0.f;
        const float* p0 = density + (ix * DYY + iy) * DZZ + iz;
        if (vx0 && vx1 && vy0 && vy1 && vz0 && vz1) {
          v2u d00 = *(const v2u*)(p0);
          v2u d01 = *(const v2u*)(p0 + DZZ);
          v2u d10 = *(const v2u*)(p0 + DYY * DZZ);
          v2u d11 = *(const v2u*)(p0 + DYY * DZZ + DZZ);
          dens += wx0 * wy0 * wz0 * d00[0];
          dens += wx0 * wy0 * fz  * d00[1];
          dens += wx0 * fy  * wz0 * d01[0];
          dens += wx0 * fy  * fz  * d01[1];
          dens += fx  * wy0 * wz0 * d10[0];
          dens += fx  * wy0 * fz  * d10[1];
          dens += fx  * fy  * wz0 * d11[0];
          dens += fx  * fy  * fz  * d11[1];
        } else {
          if (vx0 && vy0 && vz0) dens += wx0 * wy0 * wz0 * p0[0];
          if (vx0 && vy0 && vz1) dens += wx0 * wy0 * fz  * p0[1];
          if (vx0 && vy1 && vz0) dens += wx0 * fy  * wz0 * p0[DZZ];
          if (vx0 && vy1 && vz1) dens += wx0 * fy  * fz  * p0[DZZ + 1];
          if (vx1 && vy0 && vz0) dens += fx  * wy0 * wz0 * p0[DYY * DZZ];
          if (vx1 && vy0 && vz1) dens += fx  * wy0 * fz  * p0[DYY * DZZ + 1];
          if (vx1 && vy1 && vz0) dens += fx  * fy  * wz0 * p0[DYY * DZZ + DZZ];
          if (vx1 && vy1 && vz1) dens += fx  * fy  * fz  * p0[DYY * DZZ + DZZ + 1];
        }
        float u = expf(dens + ACTS);
        a = -expm1f(-0.5f * log1pf(u));   // 1-(1+u)^-0.5, no cancellation
        if (!(a > 1e-7f)) a = 0.f;
      }

      // transmittance cumprod (chunked scan + carry)
      float om = 1.f - a;
      float ip = iscan_mul(om, lane);
      float ex = __shfl_up(ip, 1); if (lane == 0) ex = 1.f;
      float wgt = a * carry * ex;
      carry *= __shfl(ip, 63);
      float w = (wgt > 1e-7f) ? wgt : 0.f;
      if (w > 0.f) pkcf += 1.f;

      // distortion-loss cumsums (exclusive)
      float wm = w * m_;
      float isw = iscan_add(w, lane);
      float iswm = iscan_add(wm, lane);
      float exw = __shfl_up(isw, 1);  if (lane == 0) exw = 0.f;
      float exwm = __shfl_up(iswm, 1); if (lane == 0) exwm = 0.f;
      sum_bi += 2.f * w * (m_ * (carryW + exw) - (carryWM + exwm));
      sum_w2 += w * w;
      carryW += __shfl(isw, 63);
      carryWM += __shfl(iswm, 63);

      // semantic trilinear, only where weight survives (w>0 implies keep)
      if (w > 0.f) {
        const float* sp0 = semantic + (size_t)((ix * DYY + iy) * DZZ + iz) * NC;
        const float* sp1 = sp0 + DYY * DZZ * NC;
#define SEM_ACC(PTR, WC)                                                        \
        { float wc = (WC);                                                      \
          const v4u* q = (const v4u*)(PTR);                                     \
          v4u q0 = q[0], q1 = q[1], q2 = q[2], q3 = q[3];                       \
          float qs = (PTR)[16];                                                 \
          out_sem[0]  += wc * q0[0];  out_sem[1]  += wc * q0[1];                \
          out_sem[2]  += wc * q0[2];  out_sem[3]  += wc * q0[3];                \
          out_sem[4]  += wc * q1[0];  out_sem[5]  += wc * q1[1];                \
          out_sem[6]  += wc * q1[2];  out_sem[7]  += wc * q1[3];                \
          out_sem[8]  += wc * q2[0];  out_sem[9]  += wc * q2[1];                \
          out_sem[10] += wc * q2[2];  out_sem[11] += wc * q2[3];                \
          out_sem[12] += wc * q3[0];  out_sem[13] += wc * q3[1];                \
          out_sem[14] += wc * q3[2];  out_sem[15] += wc * q3[3];                \
          out_sem[16] += wc * qs; }
        if (vx0 && vx1 && vy0 && vy1 && vz0 && vz1) {
          SEM_ACC(sp0,                 w * wx0 * wy0 * wz0)
          SEM_ACC(sp0 + NC,            w * wx0 * wy0 * fz)
          SEM_ACC(sp0 + DZZ * NC,      w * wx0 * fy  * wz0)
          SEM_ACC(sp0 + DZZ * NC + NC, w * wx0 * fy  * fz)
          SEM_ACC(sp1,                 w * fx  * wy0 * wz0)
          SEM_ACC(sp1 + NC,            w * fx  * wy0 * fz)
          SEM_ACC(sp1 + DZZ * NC,      w * fx  * fy  * wz0)
          SEM_ACC(sp1 + DZZ * NC + NC, w * fx  * fy  * fz)
        } else {
          if (vx0 && vy0 && vz0) SEM_ACC(sp0,                 w * wx0 * wy0 * wz0)
          if (vx0 && vy0 && vz1) SEM_ACC(sp0 + NC,            w * wx0 * wy0 * fz)
          if (vx0 && vy1 && vz0) SEM_ACC(sp0 + DZZ * NC,      w * wx0 * fy  * wz0)
          if (vx0 && vy1 && vz1) SEM_ACC(sp0 + DZZ * NC + NC, w * wx0 * fy  * fz)
          if (vx1 && vy0 && vz0) SEM_ACC(sp1,                 w * fx  * wy0 * wz0)
          if (vx1 && vy0 && vz1) SEM_ACC(sp1 + NC,            w * fx  * wy0 * fz)
          if (vx1 && vy1 && vz0) SEM_ACC(sp1 + DZZ * NC,      w * fx  * fy  * wz0)
          if (vx1 && vy1 && vz1) SEM_ACC(sp1 + DZZ * NC + NC, w * fx  * fy  * fz)
        }
#undef SEM_ACC
      }
    }

    // ---- phase G: wave reductions + per-ray epilogue -> block LDS acc ----
    float r0 = sum_bi, r1 = sum_w2, r2 = pkcf;
#pragma unroll
    for (int off = 32; off >= 1; off >>= 1) {
      r0 += __shfl_xor(r0, off);
      r1 += __shfl_xor(r1, off);
      r2 += __shfl_xor(r2, off);
#pragma unroll
      for (int j = 0; j < NC; j++) out_sem[j] += __shfl_xor(out_sem[j], off);
    }
    if (lane == 0) {
      float M = out_sem[0];
#pragma unroll
      for (int j = 1; j < NC; j++) M = fmaxf(M, out_sem[j]);
      float se = 0.f;
#pragma unroll
      for (int j = 0; j < NC; j++) se += expf(out_sem[j] - M);
      float lse = M + logf(se);
      float sy = 0.f;
#pragma unroll
      for (int j = 0; j < NC; j++) if (j == ysem) sy = out_sem[j];
      float nll = lse - sy;
      float cw = (float)(1.0 / log(c_freq[ysem] + 0.001));
      float p = fminf(fmaxf(carry, 1e-6f), 1.0f - 1e-6f);
      float ent = -(p * logf(p) + (1.f - p) * logf(1.f - p));
      atomicAdd(&s_acc[0], cw * nll);
      atomicAdd(&s_acc[1], cw);
      atomicAdd(&s_acc[2], ent);
      atomicAdd(&s_acc[3], 1.f);
      atomicAdd(&s_acc[4], r0);
      atomicAdd(&s_acc[5], r1);
      atomicAdd(&s_acc[6], r2);
    }
  }

  // block-level pre-reduction -> one set of global atomics per block
  __syncthreads();
  if (threadIdx.x == 0 && s_acc[3] > 0.f) {
#pragma unroll
    for (int i = 0; i < 7; i++) atomicAdd(&acc_g[i], s_acc[i]);
  }
}

__global__ __launch_bounds__(64) void nerf_fin(const float* __restrict__ acc,
                                               float* __restrict__ out) {
  if (threadIdx.x == 0) {
    float ls = acc[0] / fmaxf(acc[1], 1e-12f);
    float nv = fmaxf(acc[3], 1.f);
    float le = acc[2] / nv;
    float nmax = fmaxf(acc[6], 1.f);
    float ld = (acc[4] + (1.f / 3.f) * (1.f / nmax) * acc[5]) / nv;
    out[0] = 1.0f * ls;    // W_SEM
    out[1] = 0.01f * le;   // W_ENT
    out[2] = 0.01f * ld;   // W_DIST
  }
}

extern "C" void kernel_launch(void* const* d_in, const int* in_sizes, int n_in,
                              void* d_out, int out_size, void* d_ws, size_t ws_size,
                              hipStream_t stream) {
  const float* density = (const float*)d_in[0];
  const float* semantic = (const float*)d_in[1];
  const float* rays = (const float*)d_in[2];
  const float* bda = (const float*)d_in[3];
  float* out = (float*)d_out;
  float* acc = (float*)d_ws;
  int nrays = in_sizes[2] / 10;
  nerf_zero<<<1, 256, 0, stream>>>(acc);
  int nb = (nrays + RPB - 1) / RPB;
  if (nb > NBLOCKS) nb = NBLOCKS;
  nerf_main<<<nb, 64 * RPB, 0, stream>>>(density, semantic, rays, bda, acc, nrays);
  nerf_fin<<<1, 64, 0, stream>>>(acc, out);
}

// Round 7
// 320.957 us; speedup vs baseline: 1.3314x; 1.1914x over previous
//
#include <hip/hip_runtime.h>
#include <math.h>

// NerfHead: fused ray-march + trilinear + online transmittance + 3 losses.
// R6: ONE WAVE PER BLOCK (64 threads, grid=nrays). Hardware block backfill
//     provides load balance (R3 lesson: software ray-stealing cost 76 VGPRs
//     -> occupancy 19% -> slower). R1's merged D/E/F body (48-VGPR shape),
//     ballot-assisted phase-C (bit-exact, HW-verified in R3), dwordx2 density
//     pairs, km==0 chunk skip. No __syncthreads (wave-private LDS + fences).
//     8 bins x 16-float-strided global accumulators kill atomic contention
//     (8192 blocks x 7 atomics would hammer one cache line).
// d_ws layout: bins b=0..7 at acc[b*16 + j], j: [0]=sum_wy_nll [1]=sum_wy
// [2]=sum_ent [3]=n_valid [4]=sum_bi [5]=sum_w2 [6]=n_pk

#define DXX 200
#define DYY 200
#define DZZ 16
#define NC 17
#define S_TOT 416
#define N_IN 390
#define CHUNKS 7
#define NBINS 8
#define BINSTRIDE 16

typedef float v4u __attribute__((ext_vector_type(4), aligned(4), may_alias));
typedef float v2u __attribute__((ext_vector_type(2), aligned(4), may_alias));

__constant__ double c_freq[NC] = {1163161.0, 2309034.0, 188743.0, 2997643.0,
  20317180.0, 852476.0, 243808.0, 2457947.0, 497017.0, 2731022.0, 7224789.0,
  214411435.0, 5565043.0, 63191967.0, 76098082.0, 128860031.0, 141625221.0};

__device__ __forceinline__ float iscan_add(float x, int lane) {
#pragma unroll
  for (int off = 1; off < 64; off <<= 1) {
    float y = __shfl_up(x, off);
    if (lane >= off) x += y;
  }
  return x;
}
__device__ __forceinline__ float iscan_mul(float x, int lane) {
#pragma unroll
  for (int off = 1; off < 64; off <<= 1) {
    float y = __shfl_up(x, off);
    if (lane >= off) x *= y;
  }
  return x;
}

__global__ __launch_bounds__(256) void nerf_zero(float* acc) {
  if (threadIdx.x < NBINS * BINSTRIDE) acc[threadIdx.x] = 0.f;
}

__global__ __launch_bounds__(64) void nerf_main(
    const float* __restrict__ density,
    const float* __restrict__ semantic,
    const float* __restrict__ rays,
    const float* __restrict__ bda,
    float* __restrict__ acc_g,
    int nrays) {
  __shared__ float s_t[CHUNKS * 64];
  __shared__ float s_dist[S_TOT];
  __shared__ unsigned long long s_keep[CHUNKS];
  __shared__ unsigned long long s_big[CHUNKS];

  const int lane = threadIdx.x;
  const int ray = blockIdx.x;
  if (ray >= nrays) return;

  // ---- constants matching the reference's numpy derivations ----
  const double BG = (double)(1.0f / 39.0f);
  const float BGf = (float)BG;
  const float DTH = (float)((2.0 + 2.0 * BG) / 200.0 * 0.5 * 0.95);
  const float xminf = (float)(-1.0 - BG);
  const float zf = 6.4f / 80.0f;
  const float sxy = 199.0f / ((float)(1.0 + BG) - xminf);
  const float szc = 15.0f / (zf + zf);
  const float ACTS = -13.815509557964274f;

  const float* rp = rays + (size_t)ray * 10;
  float dep = rp[2];
  if (!((dep > 0.f) && (dep <= 52.f))) return;
  int ysem = (int)rp[3];
  ysem = ysem < 0 ? 0 : (ysem > NC - 1 ? NC - 1 : ysem);
  const float czc = (-1.0f + 5.4f) * 0.5f;
  float rox = rp[4] / 39.0f;
  float roy = rp[5] / 39.0f;
  float roz = (rp[6] - czc) / 39.0f;
  float d0 = rp[7], d1 = rp[8], d2 = rp[9];
  float rn = sqrtf(d0 * d0 + d1 * d1 + d2 * d2);
  float rdx = d0 / rn, rdy = d1 / rn, rdz = d2 / rn;

  // ---- t table (wave-private; 7 iterations per lane) ----
  for (int i = lane; i < CHUNKS * 64; i += 64) {
    double td;
    if (i < N_IN) {
      td = (2.0 * i + 1.0) / 390.0;
    } else {
      int j = i - N_IN;
      const double stp = (1.0 / 64.0 - 1.0) / 26.0;
      double l0 = 1.0 + j * stp;
      double l1 = (j + 1 >= 26) ? (1.0 / 64.0) : (1.0 + (j + 1) * stp);
      td = 1.0 / l0 + 1.0 / l1;
    }
    s_t[i] = (float)td;
  }
  asm volatile("s_waitcnt lgkmcnt(0)" ::: "memory");

  const float b00 = bda[0], b01 = bda[1], b02 = bda[2];
  const float b10 = bda[3], b11 = bda[4], b12 = bda[5];
  const float b20 = bda[6], b21 = bda[7], b22 = bda[8];

  auto compute_pt = [&](int s, float& tx, float& ty, float& tz, float& tt,
                        bool& inner) {
    tt = s_t[s];
    float qx = rox + rdx * tt;
    float qy = roy + rdy * tt;
    float qz = roz + rdz * tt;
    float nr = sqrtf(qx * qx + qy * qy + qz * qz);
    inner = (nr <= 1.0f) && (s < S_TOT);
    if (nr > 1.0f) {
      float sc = (1.0f + BGf - BGf / nr) / nr;
      qx *= sc; qy *= sc; qz *= sc;
    }
    tx = b00 * qx + b01 * qy + b02 * qz;
    ty = b10 * qx + b11 * qy + b12 * qz;
    tz = b20 * qx + b21 * qy + b22 * qz;
  };

  // ---- phase A/B: pts, inner+big ballots, consecutive distances -> LDS ----
  for (int c = 0; c < CHUNKS; c++) {
    int s = c * 64 + lane;
    float tx, ty, tz, tt; bool inner;
    compute_pt(s, tx, ty, tz, tt, inner);
    unsigned long long bal = __ballot(inner);
    float nx = __shfl(tx, lane + 1);
    float ny = __shfl(ty, lane + 1);
    float nz = __shfl(tz, lane + 1);
    if (c < CHUNKS - 1) {
      float hx, hy, hz, ht; bool hi;
      compute_pt((c + 1) * 64, hx, hy, hz, ht, hi);
      if (lane == 63) { nx = hx; ny = hy; nz = hz; }
    }
    float ex = nx - tx, ey = ny - ty, ez = nz - tz;
    float dd = sqrtf(ex * ex + ey * ey + ez * ez);
    bool dlive = (s < S_TOT - 1);
    if (dlive) s_dist[s] = dd;
    unsigned long long db = __ballot(dlive && (dd > DTH));
    if (lane == 0) { s_keep[c] = bal; s_big[c] = db; }
  }

  // ---- phase C: resetting distance scan, serial ONLY over non-big steps.
  // big step (dist > DTH) forces over=1, cum=0 regardless of incoming cum
  // (f32 add of non-negatives is monotone) -> bit-exact decomposition.
  asm volatile("s_waitcnt lgkmcnt(0)" ::: "memory");
  if (lane == 0) {
    float cum = 0.f;
    int prev = 0;
    unsigned long long carrybit = 0;
#pragma unroll
    for (int c = 0; c < CHUNKS; c++) {
      unsigned long long inner = s_keep[c];
      unsigned long long db = s_big[c];
      unsigned long long big = (db << 1) | carrybit;
      carrybit = db >> 63;
      unsigned long long valid = ~0ull;
      if (c == 0) valid &= ~1ull;                       // s=0 is not a step
      if (c == CHUNKS - 1) valid &= 0x00000000FFFFFFFFull;  // s<=415
      big &= valid;
      unsigned long long k = inner | big;
      unsigned long long nb = valid & ~big;
      while (nb) {
        int b = __ffsll((unsigned long long)nb) - 1;
        nb &= nb - 1;
        int s = c * 64 + b;
        if (s - 1 != prev) cum = 0.f;   // gap => previous step was big (reset)
        cum += s_dist[s - 1];
        if (cum > DTH) { cum = 0.f; k |= 1ull << b; }
        prev = s;
      }
      s_keep[c] = k;
    }
  }
  asm volatile("s_waitcnt lgkmcnt(0)" ::: "memory");

  // ---- phase D/E/F merged: density->alpha, scans, semantic (one loop) ----
  float out_sem[NC];
#pragma unroll
  for (int j = 0; j < NC; j++) out_sem[j] = 0.f;
  float carry = 1.f, carryW = 0.f, carryWM = 0.f;
  float sum_bi = 0.f, sum_w2 = 0.f, pkcf = 0.f;

  for (int c = 0; c < CHUNKS; c++) {
    unsigned long long km = s_keep[c];
    if (km == 0ull) continue;   // exact identity: a==0 => carries unchanged
    int s = c * 64 + lane;
    float tx, ty, tz, tt; bool inner;
    compute_pt(s, tx, ty, tz, tt, inner);
    float m_ = 1.0f - 1.0f / (1.0f + tt);
    bool keep = (km >> lane) & 1ull;

    float gx = (tx - xminf) * sxy;
    float gy = (ty - xminf) * sxy;
    float gz = (tz + zf) * szc;
    float hxf = floorf(gx), hyf = floorf(gy), hzf = floorf(gz);
    int ix = (int)hxf, iy = (int)hyf, iz = (int)hzf;
    float fx = gx - hxf, fy = gy - hyf, fz = gz - hzf;
    float wx0 = 1.f - fx, wy0 = 1.f - fy, wz0 = 1.f - fz;
    bool vx0 = (unsigned)ix < (unsigned)DXX, vx1 = (unsigned)(ix + 1) < (unsigned)DXX;
    bool vy0 = (unsigned)iy < (unsigned)DYY, vy1 = (unsigned)(iy + 1) < (unsigned)DYY;
    bool vz0 = (unsigned)iz < (unsigned)DZZ, vz1 = (unsigned)(iz + 1) < (unsigned)DZZ;

    float a = 0.f;
    if (keep) {
      float dens = 0.f;
      const float* p0 = density + (ix * DYY + iy) * DZZ + iz;
      if (vx0 && vx1 && vy0 && vy1 && vz0 && vz1) {
        v2u d00 = *(const v2u*)(p0);
        v2u d01 = *(const v2u*)(p0 + DZZ);
        v2u d10 = *(const v2u*)(p0 + DYY * DZZ);
        v2u d11 = *(const v2u*)(p0 + DYY * DZZ + DZZ);
        dens += wx0 * wy0 * wz0 * d00[0];
        dens += wx0 * wy0 * fz  * d00[1];
        dens += wx0 * fy  * wz0 * d01[0];
        dens += wx0 * fy  * fz  * d01[1];
        dens += fx  * wy0 * wz0 * d10[0];
        dens += fx  * wy0 * fz  * d10[1];
        dens += fx  * fy  * wz0 * d11[0];
        dens += fx  * fy  * fz  * d11[1];
      } else {
        if (vx0 && vy0 && vz0) dens += wx0 * wy0 * wz0 * p0[0];
        if (vx0 && vy0 && vz1) dens += wx0 * wy0 * fz  * p0[1];
        if (vx0 && vy1 && vz0) dens += wx0 * fy  * wz0 * p0[DZZ];
        if (vx0 && vy1 && vz1) dens += wx0 * fy  * fz  * p0[DZZ + 1];
        if (vx1 && vy0 && vz0) dens += fx  * wy0 * wz0 * p0[DYY * DZZ];
        if (vx1 && vy0 && vz1) dens += fx  * wy0 * fz  * p0[DYY * DZZ + 1];
        if (vx1 && vy1 && vz0) dens += fx  * fy  * wz0 * p0[DYY * DZZ + DZZ];
        if (vx1 && vy1 && vz1) dens += fx  * fy  * fz  * p0[DYY * DZZ + DZZ + 1];
      }
      float u = expf(dens + ACTS);
      a = -expm1f(-0.5f * log1pf(u));   // 1-(1+u)^-0.5, no cancellation
      if (!(a > 1e-7f)) a = 0.f;
    }

    // transmittance cumprod (chunked scan + carry)
    float om = 1.f - a;
    float ip = iscan_mul(om, lane);
    float ex = __shfl_up(ip, 1); if (lane == 0) ex = 1.f;
    float wgt = a * carry * ex;
    carry *= __shfl(ip, 63);
    float w = (wgt > 1e-7f) ? wgt : 0.f;
    if (w > 0.f) pkcf += 1.f;

    // distortion-loss cumsums (exclusive)
    float wm = w * m_;
    float isw = iscan_add(w, lane);
    float iswm = iscan_add(wm, lane);
    float exw = __shfl_up(isw, 1);  if (lane == 0) exw = 0.f;
    float exwm = __shfl_up(iswm, 1); if (lane == 0) exwm = 0.f;
    sum_bi += 2.f * w * (m_ * (carryW + exw) - (carryWM + exwm));
    sum_w2 += w * w;
    carryW += __shfl(isw, 63);
    carryWM += __shfl(iswm, 63);

    // semantic trilinear, only where weight survives (w>0 implies keep)
    if (w > 0.f) {
      const float* sp0 = semantic + (size_t)((ix * DYY + iy) * DZZ + iz) * NC;
      const float* sp1 = sp0 + DYY * DZZ * NC;
#define SEM_ACC(PTR, WC)                                                        \
      { float wc = (WC);                                                        \
        const v4u* q = (const v4u*)(PTR);                                       \
        v4u q0 = q[0], q1 = q[1], q2 = q[2], q3 = q[3];                         \
        float qs = (PTR)[16];                                                   \
        out_sem[0]  += wc * q0[0];  out_sem[1]  += wc * q0[1];                  \
        out_sem[2]  += wc * q0[2];  out_sem[3]  += wc * q0[3];                  \
        out_sem[4]  += wc * q1[0];  out_sem[5]  += wc * q1[1];                  \
        out_sem[6]  += wc * q1[2];  out_sem[7]  += wc * q1[3];                  \
        out_sem[8]  += wc * q2[0];  out_sem[9]  += wc * q2[1];                  \
        out_sem[10] += wc * q2[2];  out_sem[11] += wc * q2[3];                  \
        out_sem[12] += wc * q3[0];  out_sem[13] += wc * q3[1];                  \
        out_sem[14] += wc * q3[2];  out_sem[15] += wc * q3[3];                  \
        out_sem[16] += wc * qs; }
      if (vx0 && vx1 && vy0 && vy1 && vz0 && vz1) {
        SEM_ACC(sp0,                 w * wx0 * wy0 * wz0)
        SEM_ACC(sp0 + NC,            w * wx0 * wy0 * fz)
        SEM_ACC(sp0 + DZZ * NC,      w * wx0 * fy  * wz0)
        SEM_ACC(sp0 + DZZ * NC + NC, w * wx0 * fy  * fz)
        SEM_ACC(sp1,                 w * fx  * wy0 * wz0)
        SEM_ACC(sp1 + NC,            w * fx  * wy0 * fz)
        SEM_ACC(sp1 + DZZ * NC,      w * fx  * fy  * wz0)
        SEM_ACC(sp1 + DZZ * NC + NC, w * fx  * fy  * fz)
      } else {
        if (vx0 && vy0 && vz0) SEM_ACC(sp0,                 w * wx0 * wy0 * wz0)
        if (vx0 && vy0 && vz1) SEM_ACC(sp0 + NC,            w * wx0 * wy0 * fz)
        if (vx0 && vy1 && vz0) SEM_ACC(sp0 + DZZ * NC,      w * wx0 * fy  * wz0)
        if (vx0 && vy1 && vz1) SEM_ACC(sp0 + DZZ * NC + NC, w * wx0 * fy  * fz)
        if (vx1 && vy0 && vz0) SEM_ACC(sp1,                 w * fx  * wy0 * wz0)
        if (vx1 && vy0 && vz1) SEM_ACC(sp1 + NC,            w * fx  * wy0 * fz)
        if (vx1 && vy1 && vz0) SEM_ACC(sp1 + DZZ * NC,      w * fx  * fy  * wz0)
        if (vx1 && vy1 && vz1) SEM_ACC(sp1 + DZZ * NC + NC, w * fx  * fy  * fz)
      }
#undef SEM_ACC
    }
  }

  // ---- phase G: wave reductions + per-ray epilogue -> binned atomics ----
  float r0 = sum_bi, r1 = sum_w2, r2 = pkcf;
#pragma unroll
  for (int off = 32; off >= 1; off >>= 1) {
    r0 += __shfl_xor(r0, off);
    r1 += __shfl_xor(r1, off);
    r2 += __shfl_xor(r2, off);
#pragma unroll
    for (int j = 0; j < NC; j++) out_sem[j] += __shfl_xor(out_sem[j], off);
  }
  if (lane == 0) {
    float M = out_sem[0];
#pragma unroll
    for (int j = 1; j < NC; j++) M = fmaxf(M, out_sem[j]);
    float se = 0.f;
#pragma unroll
    for (int j = 0; j < NC; j++) se += expf(out_sem[j] - M);
    float lse = M + logf(se);
    float sy = 0.f;
#pragma unroll
    for (int j = 0; j < NC; j++) if (j == ysem) sy = out_sem[j];
    float nll = lse - sy;
    float cw = (float)(1.0 / log(c_freq[ysem] + 0.001));
    float p = fminf(fmaxf(carry, 1e-6f), 1.0f - 1e-6f);
    float ent = -(p * logf(p) + (1.f - p) * logf(1.f - p));
    float* bin = acc_g + (ray & (NBINS - 1)) * BINSTRIDE;
    atomicAdd(&bin[0], cw * nll);
    atomicAdd(&bin[1], cw);
    atomicAdd(&bin[2], ent);
    atomicAdd(&bin[3], 1.f);
    atomicAdd(&bin[4], r0);
    atomicAdd(&bin[5], r1);
    atomicAdd(&bin[6], r2);
  }
}

__global__ __launch_bounds__(64) void nerf_fin(const float* __restrict__ acc,
                                               float* __restrict__ out) {
  if (threadIdx.x == 0) {
    float t0 = 0.f, t1 = 0.f, t2 = 0.f, t3 = 0.f, t4 = 0.f, t5 = 0.f, t6 = 0.f;
#pragma unroll
    for (int b = 0; b < NBINS; b++) {
      const float* p = acc + b * BINSTRIDE;
      t0 += p[0]; t1 += p[1]; t2 += p[2]; t3 += p[3];
      t4 += p[4]; t5 += p[5]; t6 += p[6];
    }
    float ls = t0 / fmaxf(t1, 1e-12f);
    float nv = fmaxf(t3, 1.f);
    float le = t2 / nv;
    float nmax = fmaxf(t6, 1.f);
    float ld = (t4 + (1.f / 3.f) * (1.f / nmax) * t5) / nv;
    out[0] = 1.0f * ls;    // W_SEM
    out[1] = 0.01f * le;   // W_ENT
    out[2] = 0.01f * ld;   // W_DIST
  }
}

extern "C" void kernel_launch(void* const* d_in, const int* in_sizes, int n_in,
                              void* d_out, int out_size, void* d_ws, size_t ws_size,
                              hipStream_t stream) {
  const float* density = (const float*)d_in[0];
  const float* semantic = (const float*)d_in[1];
  const float* rays = (const float*)d_in[2];
  const float* bda = (const float*)d_in[3];
  float* out = (float*)d_out;
  float* acc = (float*)d_ws;
  int nrays = in_sizes[2] / 10;
  nerf_zero<<<1, 256, 0, stream>>>(acc);
  nerf_main<<<nrays, 64, 0, stream>>>(density, semantic, rays, bda, acc, nrays);
  nerf_fin<<<1, 64, 0, stream>>>(acc, out);
}